// Round 1
// baseline (550.333 us; speedup 1.0000x reference)
//
#include <hip/hip_runtime.h>

#define EPSC    1e-5f
#define LNEPS   1e-5f

typedef __attribute__((ext_vector_type(8))) short  short8;   // 8 bf16
typedef __attribute__((ext_vector_type(4))) float  floatx4;  // 4 fp32 acc

static __device__ __forceinline__ unsigned short f2bf(float f){
  union { float f; unsigned int u; } v; v.f = f;
  unsigned int u = v.u;
  u += 0x7FFFu + ((u >> 16) & 1u);   // round-to-nearest-even
  return (unsigned short)(u >> 16);
}

// ---------------------------------------------------------------------------
// K1: per-(n,c) sum/sumsq partials + per-group gram partials (bf16 MFMA).
// grid (half=2, g=4, n=32), 256 threads. Each block: 64 ch x 2048 hw.
// ---------------------------------------------------------------------------
__global__ __launch_bounds__(256) void k_stats_gram(
    const float* __restrict__ X, float* __restrict__ S1p,
    float* __restrict__ S2p, float* __restrict__ gramP)
{
  const int half = blockIdx.x, g = blockIdx.y, n = blockIdx.z;
  const int t  = threadIdx.x;
  const int ch = t >> 2, f4 = t & 3;
  __shared__ unsigned short lt[64][88];   // bf16 tile, stride 88 (176B, 16B-mult, 2-way banks)

  const float* rowb = X + (size_t)(n*256 + g*64 + ch)*4096 + half*2048;

  float4 buf[4];
  #pragma unroll
  for (int i = 0; i < 4; ++i)
    buf[i] = *(const float4*)(rowb + (4*i + f4)*4);

  float s1 = 0.f, s2 = 0.f;
  floatx4 acc[4];
  #pragma unroll
  for (int i = 0; i < 4; ++i) acc[i] = (floatx4){0.f, 0.f, 0.f, 0.f};

  const int wv = t >> 6;               // wave id: d-rows 16*wv..16*wv+15
  const int l15 = t & 15, q = (t & 63) >> 4;

  for (int tile = 0; tile < 32; ++tile){
    #pragma unroll
    for (int i = 0; i < 4; ++i){
      float4 v = buf[i];
      s1 += (v.x + v.y) + (v.z + v.w);
      s2 += v.x*v.x + v.y*v.y + v.z*v.z + v.w*v.w;
      ushort4 b;
      b.x = f2bf(v.x); b.y = f2bf(v.y); b.z = f2bf(v.z); b.w = f2bf(v.w);
      *(ushort4*)&lt[ch][(4*i + f4)*4] = b;
    }
    __syncthreads();
    if (tile < 31){
      const float* nb = rowb + (tile + 1)*64;
      #pragma unroll
      for (int i = 0; i < 4; ++i)
        buf[i] = *(const float4*)(nb + (4*i + f4)*4);
    }
    #pragma unroll
    for (int k0 = 0; k0 < 64; k0 += 32){
      short8 af = *(const short8*)&lt[16*wv + l15][k0 + q*8];
      #pragma unroll
      for (int t4 = 0; t4 < 4; ++t4){
        short8 bf = *(const short8*)&lt[16*t4 + l15][k0 + q*8];
        acc[t4] = __builtin_amdgcn_mfma_f32_16x16x32_bf16(af, bf, acc[t4], 0, 0, 0);
      }
    }
    __syncthreads();
  }

  // stats: 4 consecutive lanes share a channel
  s1 += __shfl_down(s1, 2); s1 += __shfl_down(s1, 1);
  s2 += __shfl_down(s2, 2); s2 += __shfl_down(s2, 1);
  const int blk = n*8 + g*2 + half;
  if (f4 == 0){ S1p[blk*64 + ch] = s1; S2p[blk*64 + ch] = s2; }

  // gram partial write: C/D layout col=lane&15, row=4*quad+reg (m89/m91 verified)
  float* gp = gramP + (size_t)blk*4096;
  #pragma unroll
  for (int t4 = 0; t4 < 4; ++t4)
    #pragma unroll
    for (int r = 0; r < 4; ++r)
      gp[(16*wv + 4*q + r)*64 + 16*t4 + l15] = acc[t4][r];
}

// 64x64 fp32 matmul in LDS (stride 64), 1024 threads: thread -> 1x4 of C.
static __device__ __forceinline__ void mm64(const float* __restrict__ A,
                                            const float* __restrict__ B,
                                            float* __restrict__ C, int t)
{
  const int d = t >> 4, e0 = (t & 15) << 2;
  float ax = 0.f, ay = 0.f, az = 0.f, aw = 0.f;
  const float* Ar = A + d*64;
  #pragma unroll
  for (int k = 0; k < 64; ++k){
    const float a = Ar[k];
    const float* Bp = B + k*64 + e0;
    ax += a * Bp[0]; ay += a * Bp[1]; az += a * Bp[2]; aw += a * Bp[3];
  }
  C[d*64 + e0 + 0] = ax; C[d*64 + e0 + 1] = ay;
  C[d*64 + e0 + 2] = az; C[d*64 + e0 + 3] = aw;
}

// ---------------------------------------------------------------------------
// K2: grid=5, 1024 threads.
//   blocks 0..3 : reduce gram -> Sigma_N -> Newton-Schulz(3) -> Pw = w*P
//   block  4    : x_var -> fc1 -> LN -> relu -> fc2 -> sigmoid -> a = (1-w)*y/scale
// ---------------------------------------------------------------------------
__global__ __launch_bounds__(1024) void k_mid(
    const float* __restrict__ S1p, const float* __restrict__ S2p,
    const float* __restrict__ gramP,
    const float* __restrict__ fc1_w, const float* __restrict__ ln_g,
    const float* __restrict__ ln_b, const float* __restrict__ fc2_w,
    const float* __restrict__ xw,
    float* __restrict__ Pw, float* __restrict__ aOut)
{
  __shared__ float sm[16384];   // exactly 64 KiB
  const int t = threadIdx.x;
  const float w = 1.f / (1.f + __expf(-xw[0]));

  if (blockIdx.x < 4){
    // -------- Newton-Schulz path --------
    const int g = blockIdx.x;
    float* SN = sm;            // 4096
    float* P  = sm + 4096;
    float* T1 = sm + 8192;
    float* T2 = sm + 12288;
    float* cm  = T1;           // 64  (dead before T1 is written)
    float* rtr = T1 + 64;

    if (t < 64){
      float s = 0.f;
      for (int n = 0; n < 32; ++n){
        const float* p = S1p + (n*8 + g*2)*64 + t;
        s += p[0] + p[64];
      }
      cm[t] = s * (1.f/131072.f);
    }
    __syncthreads();

    #pragma unroll
    for (int i = 0; i < 4; ++i){
      const int idx = t + i*1024;
      const int d = idx >> 6, e = idx & 63;
      float s = 0.f;
      for (int n = 0; n < 32; ++n){
        const float* p = gramP + (size_t)(n*8 + g*2)*4096 + idx;
        s += p[0] + p[4096];
      }
      // Sigma = (1/m) I + EPS * (gram - m*mean_d*mean_e)
      float sig = EPSC * (s - 131072.f * cm[d] * cm[e]);
      if (d == e) sig += (1.f/131072.f);
      SN[idx] = sig;
    }
    __syncthreads();

    if (t < 64){   // trace over diag (threads 0..63 = wave 0)
      float v = SN[t*64 + t];
      v += __shfl_down(v, 32); v += __shfl_down(v, 16);
      v += __shfl_down(v, 8);  v += __shfl_down(v, 4);
      v += __shfl_down(v, 2);  v += __shfl_down(v, 1);
      if (t == 0) rtr[0] = 1.f / v;
    }
    __syncthreads();
    const float rT = rtr[0];

    #pragma unroll
    for (int i = 0; i < 4; ++i){
      const int idx = t + i*1024;
      SN[idx] *= rT;
      P[idx] = ((idx >> 6) == (idx & 63)) ? 1.f : 0.f;
    }
    __syncthreads();

    for (int it = 0; it < 3; ++it){
      mm64(P,  P,  T1, t); __syncthreads();
      mm64(T1, P,  T2, t); __syncthreads();   // T2 = P^3
      mm64(T2, SN, T1, t); __syncthreads();   // T1 = P^3 @ Sigma_N
      #pragma unroll
      for (int i = 0; i < 4; ++i){
        const int idx = t + i*1024;
        P[idx] = -0.5f * P[idx] + 1.5f * T1[idx];
      }
      __syncthreads();
    }
    #pragma unroll
    for (int i = 0; i < 4; ++i){
      const int idx = t + i*1024;
      Pw[g*4096 + idx] = w * P[idx];
    }
  } else {
    // -------- squeeze-excite path --------
    float* xv  = sm;            // 8192
    float* h   = sm + 8192;     // 2048
    float* hn  = sm + 10240;    // 2048
    float* red = sm + 12288;    // 1024

    float lsum = 0.f;
    #pragma unroll
    for (int i = 0; i < 8; ++i){
      const int idx = t + i*1024;
      const int n = idx >> 8, c = idx & 255;
      const int base = (n*8 + (c >> 6)*2)*64 + (c & 63);
      const float s1 = S1p[base] + S1p[base + 64];
      const float s2 = S2p[base] + S2p[base + 64];
      const float v = (s2 - s1*s1*(1.f/4096.f)) * (1.f/4095.f);  // ddof=1
      xv[idx] = v; lsum += v;
    }
    red[t] = lsum;
    __syncthreads();
    for (int s = 512; s > 0; s >>= 1){
      if (t < s) red[t] += red[t + s];
      __syncthreads();
    }
    const float scale = sqrtf(red[0] * (1.f/8192.f));

    #pragma unroll
    for (int i = 0; i < 2; ++i){
      const int idx = t + i*1024;
      const int n = idx >> 6, j = idx & 63;
      const float* xr = xv + n*256;
      const float* fr = fc1_w + j*256;
      float s = 0.f;
      for (int c = 0; c < 256; ++c) s += xr[c] * fr[c];
      h[idx] = s;
    }
    __syncthreads();
    if (t < 32){
      const float* hr = h + t*64;
      float mu = 0.f, m2 = 0.f;
      for (int j = 0; j < 64; ++j) mu += hr[j];
      mu *= (1.f/64.f);
      for (int j = 0; j < 64; ++j){ float d = hr[j] - mu; m2 += d*d; }
      m2 *= (1.f/64.f);                         // biased (LayerNorm)
      red[t] = mu; red[64 + t] = rsqrtf(m2 + LNEPS);
    }
    __syncthreads();
    #pragma unroll
    for (int i = 0; i < 2; ++i){
      const int idx = t + i*1024;
      const int n = idx >> 6, j = idx & 63;
      float v = (h[idx] - red[n]) * red[64 + n] * ln_g[j] + ln_b[j];
      hn[idx] = v > 0.f ? v : 0.f;
    }
    __syncthreads();
    const float ascl = (1.f - w) / scale;
    #pragma unroll
    for (int i = 0; i < 8; ++i){
      const int idx = t + i*1024;
      const int n = idx >> 8, c = idx & 255;
      const float* hr = hn + n*64;
      const float* fr = fc2_w + c*64;
      float s = 0.f;
      for (int j = 0; j < 64; ++j) s += hr[j] * fr[j];
      const float y = 1.f / (1.f + __expf(-s));
      aOut[idx] = ascl * y;
    }
  }
}

// ---------------------------------------------------------------------------
// K3: out[n,g*64+d,hw] = sum_e Pw[g][d][e]*X[n,g*64+e,hw] + a[n,c]*X[n,c,hw]
// grid (hwtile=32, g=4, n=32), 256 threads, 128-hw tiles.
// ---------------------------------------------------------------------------
__global__ __launch_bounds__(256) void k_final(
    const float* __restrict__ X, const float* __restrict__ Pw,
    const float* __restrict__ aIn, float* __restrict__ out)
{
  const int bx = blockIdx.x, g = blockIdx.y, n = blockIdx.z;
  const int t = threadIdx.x;
  __shared__ float xt[64*132];   // 64 ch x 128 hw, stride 132
  __shared__ float Pl[4096];
  __shared__ float al[64];

  {
    const int ch = t >> 2, f4 = t & 3;
    const float* rowb = X + (size_t)(n*256 + g*64 + ch)*4096 + bx*128;
    float* ld = xt + ch*132;
    #pragma unroll
    for (int i = 0; i < 8; ++i){
      const int col = (4*i + f4)*4;
      *(float4*)(ld + col) = *(const float4*)(rowb + col);
    }
  }
  #pragma unroll
  for (int i = 0; i < 16; ++i)
    Pl[t + 256*i] = Pw[g*4096 + t + 256*i];
  if (t < 64) al[t] = aIn[n*256 + g*64 + t];
  __syncthreads();

  const int hwq = t & 31, og = t >> 5;    // 4 hw cols, 8 out channels
  const float* xcol = xt + hwq*4;
  float4 acc[8];
  #pragma unroll
  for (int dd = 0; dd < 8; ++dd){
    const int d = og*8 + dd;
    float4 xv = *(const float4*)(xcol + d*132);
    const float av = al[d];
    acc[dd].x = av*xv.x; acc[dd].y = av*xv.y; acc[dd].z = av*xv.z; acc[dd].w = av*xv.w;
  }
  for (int e4 = 0; e4 < 16; ++e4){
    float4 x0 = *(const float4*)(xcol + (e4*4 + 0)*132);
    float4 x1 = *(const float4*)(xcol + (e4*4 + 1)*132);
    float4 x2 = *(const float4*)(xcol + (e4*4 + 2)*132);
    float4 x3 = *(const float4*)(xcol + (e4*4 + 3)*132);
    #pragma unroll
    for (int dd = 0; dd < 8; ++dd){
      const int d = og*8 + dd;
      float4 p = *(const float4*)(Pl + d*64 + e4*4);
      acc[dd].x += p.x*x0.x + p.y*x1.x + p.z*x2.x + p.w*x3.x;
      acc[dd].y += p.x*x0.y + p.y*x1.y + p.z*x2.y + p.w*x3.y;
      acc[dd].z += p.x*x0.z + p.y*x1.z + p.z*x2.z + p.w*x3.z;
      acc[dd].w += p.x*x0.w + p.y*x1.w + p.z*x2.w + p.w*x3.w;
    }
  }
  float* ob = out + (size_t)(n*256 + g*64)*4096 + bx*128 + hwq*4;
  #pragma unroll
  for (int dd = 0; dd < 8; ++dd)
    *(float4*)(ob + (size_t)(og*8 + dd)*4096) = acc[dd];
}

// ---------------------------------------------------------------------------
extern "C" void kernel_launch(void* const* d_in, const int* in_sizes, int n_in,
                              void* d_out, int out_size, void* d_ws, size_t ws_size,
                              hipStream_t stream)
{
  const float* X     = (const float*)d_in[0];
  const float* fc1_w = (const float*)d_in[1];
  const float* ln_g  = (const float*)d_in[2];
  const float* ln_b  = (const float*)d_in[3];
  const float* fc2_w = (const float*)d_in[4];
  const float* xw    = (const float*)d_in[5];
  float* out = (float*)d_out;

  char* ws = (char*)d_ws;
  float* gramP = (float*)ws;                  // 256*4096*4 = 4 MiB
  float* S1p   = (float*)(ws + 4194304);      // 64 KiB
  float* S2p   = (float*)(ws + 4259840);      // 64 KiB
  float* Pwb   = (float*)(ws + 4325376);      // 64 KiB
  float* aB    = (float*)(ws + 4390912);      // 32 KiB

  k_stats_gram<<<dim3(2, 4, 32), 256, 0, stream>>>(X, S1p, S2p, gramP);
  k_mid<<<5, 1024, 0, stream>>>(S1p, S2p, gramP, fc1_w, ln_g, ln_b, fc2_w, xw, Pwb, aB);
  k_final<<<dim3(32, 4, 32), 256, 0, stream>>>(X, Pwb, aB, out);
}

// Round 2
// 318.277 us; speedup vs baseline: 1.7291x; 1.7291x over previous
//
#include <hip/hip_runtime.h>

#define EPSC    1e-5f
#define LNEPS   1e-5f

typedef __attribute__((ext_vector_type(8))) short  short8;   // 8 bf16
typedef __attribute__((ext_vector_type(4))) float  floatx4;  // 4 fp32 acc

static __device__ __forceinline__ unsigned short f2bf(float f){
  union { float f; unsigned int u; } v; v.f = f;
  unsigned int u = v.u;
  u += 0x7FFFu + ((u >> 16) & 1u);   // round-to-nearest-even
  return (unsigned short)(u >> 16);
}
static __device__ __forceinline__ float bf2f(unsigned short h){
  union { unsigned int u; float f; } v; v.u = ((unsigned int)h) << 16;
  return v.f;
}

// ---------------------------------------------------------------------------
// K1: per-(n,c) sum/sumsq partials + per-group gram partials (bf16 MFMA).
// grid (half=2, g=4, n=32), 256 threads. Each block: 64 ch x 2048 hw.
// ---------------------------------------------------------------------------
__global__ __launch_bounds__(256) void k_stats_gram(
    const float* __restrict__ X, float* __restrict__ S1p,
    float* __restrict__ S2p, float* __restrict__ gramP)
{
  const int half = blockIdx.x, g = blockIdx.y, n = blockIdx.z;
  const int t  = threadIdx.x;
  const int ch = t >> 2, f4 = t & 3;
  __shared__ unsigned short lt[64][88];   // bf16 tile, stride 88

  const float* rowb = X + (size_t)(n*256 + g*64 + ch)*4096 + half*2048;

  float4 buf[4];
  #pragma unroll
  for (int i = 0; i < 4; ++i)
    buf[i] = *(const float4*)(rowb + (4*i + f4)*4);

  float s1 = 0.f, s2 = 0.f;
  floatx4 acc[4];
  #pragma unroll
  for (int i = 0; i < 4; ++i) acc[i] = (floatx4){0.f, 0.f, 0.f, 0.f};

  const int wv = t >> 6;
  const int l15 = t & 15, q = (t & 63) >> 4;

  for (int tile = 0; tile < 32; ++tile){
    #pragma unroll
    for (int i = 0; i < 4; ++i){
      float4 v = buf[i];
      s1 += (v.x + v.y) + (v.z + v.w);
      s2 += v.x*v.x + v.y*v.y + v.z*v.z + v.w*v.w;
      ushort4 b;
      b.x = f2bf(v.x); b.y = f2bf(v.y); b.z = f2bf(v.z); b.w = f2bf(v.w);
      *(ushort4*)&lt[ch][(4*i + f4)*4] = b;
    }
    __syncthreads();
    if (tile < 31){
      const float* nb = rowb + (tile + 1)*64;
      #pragma unroll
      for (int i = 0; i < 4; ++i)
        buf[i] = *(const float4*)(nb + (4*i + f4)*4);
    }
    #pragma unroll
    for (int k0 = 0; k0 < 64; k0 += 32){
      short8 af = *(const short8*)&lt[16*wv + l15][k0 + q*8];
      #pragma unroll
      for (int t4 = 0; t4 < 4; ++t4){
        short8 bf = *(const short8*)&lt[16*t4 + l15][k0 + q*8];
        acc[t4] = __builtin_amdgcn_mfma_f32_16x16x32_bf16(af, bf, acc[t4], 0, 0, 0);
      }
    }
    __syncthreads();
  }

  s1 += __shfl_down(s1, 2); s1 += __shfl_down(s1, 1);
  s2 += __shfl_down(s2, 2); s2 += __shfl_down(s2, 1);
  const int blk = n*8 + g*2 + half;
  if (f4 == 0){ S1p[blk*64 + ch] = s1; S2p[blk*64 + ch] = s2; }

  float* gp = gramP + (size_t)blk*4096;
  #pragma unroll
  for (int t4 = 0; t4 < 4; ++t4)
    #pragma unroll
    for (int r = 0; r < 4; ++r)
      gp[(16*wv + 4*q + r)*64 + 16*t4 + l15] = acc[t4][r];
}

// ---------------------------------------------------------------------------
// K2: parallel reductions. blocks 0..63: gram -> SigmaS (raw). block 64:
// x_var (8192), total var sum, cmean (256).
// ---------------------------------------------------------------------------
__global__ __launch_bounds__(256) void k_reduce(
    const float* __restrict__ gramP, const float* __restrict__ S1p,
    const float* __restrict__ S2p,
    float* __restrict__ SigmaS, float* __restrict__ xvar,
    float* __restrict__ cmean, float* __restrict__ vsum)
{
  const int t = threadIdx.x, b = blockIdx.x;
  if (b < 64){
    const int idx = b*256 + t;              // [0, 16384)
    const int g = idx >> 12, e = idx & 4095;
    const float* p = gramP + (size_t)(g*2)*4096 + e;
    float s = 0.f;
    for (int n = 0; n < 32; ++n){ s += p[0] + p[4096]; p += 8*4096; }
    SigmaS[idx] = s;
  } else {
    __shared__ float red[256];
    float lsum = 0.f;
    #pragma unroll
    for (int i = 0; i < 32; ++i){
      const int idx = t + i*256;            // [0, 8192)
      const int n = idx >> 8, c = idx & 255;
      const int base = (n*8 + (c >> 6)*2)*64 + (c & 63);
      const float s1 = S1p[base] + S1p[base + 64];
      const float s2 = S2p[base] + S2p[base + 64];
      const float v = (s2 - s1*s1*(1.f/4096.f)) * (1.f/4095.f);
      xvar[idx] = v; lsum += v;
    }
    red[t] = lsum;
    __syncthreads();
    for (int s = 128; s > 0; s >>= 1){
      if (t < s) red[t] += red[t + s];
      __syncthreads();
    }
    if (t == 0) vsum[0] = red[0];
    // cmean[g*64+cc]
    {
      const int g = t >> 6, cc = t & 63;
      float s = 0.f;
      for (int n = 0; n < 32; ++n){
        const float* p = S1p + (n*8 + g*2)*64 + cc;
        s += p[0] + p[64];
      }
      cmean[t] = s * (1.f/131072.f);
    }
  }
}

// ---------------------------------------------------------------------------
// K3: blocks 0..3 = Newton-Schulz (MFMA, split-bf16); blocks 4..35 = SE (per-n)
// 256 threads.
// ---------------------------------------------------------------------------
#define STR 72   // bf16 row stride (ushorts)

__global__ __launch_bounds__(256) void k_mid2(
    const float* __restrict__ SigmaS, const float* __restrict__ cmean,
    const float* __restrict__ xvar, const float* __restrict__ vsum,
    const float* __restrict__ fc1_w, const float* __restrict__ ln_g,
    const float* __restrict__ ln_b, const float* __restrict__ fc2_w,
    const float* __restrict__ xw,
    float* __restrict__ Pw, float* __restrict__ aOut)
{
  __shared__ __align__(16) unsigned short us[6*64*STR];   // SNh SNl Ph Pl Th Tl
  __shared__ float fbuf[512];
  const int t = threadIdx.x;
  const float wsig = 1.f / (1.f + __expf(-xw[0]));

  if (blockIdx.x < 4){
    // ---------------- Newton-Schulz ----------------
    const int g = blockIdx.x;
    const int w4 = t >> 6, l15 = t & 15, q = (t & 63) >> 4;
    unsigned short* SNh = us;
    unsigned short* SNl = us + 1*64*STR;
    unsigned short* Ph  = us + 2*64*STR;
    unsigned short* Pl_ = us + 3*64*STR;
    unsigned short* Th  = us + 4*64*STR;
    unsigned short* Tl  = us + 5*64*STR;
    float* cml = fbuf;          // 64
    float* rtr = fbuf + 64;

    if (t < 64) cml[t] = cmean[g*64 + t];
    __syncthreads();
    if (t < 64){
      const float cm = cml[t];
      float v = EPSC * (SigmaS[g*4096 + t*65] - 131072.f*cm*cm) + (1.f/131072.f);
      v += __shfl_xor(v, 32); v += __shfl_xor(v, 16);
      v += __shfl_xor(v, 8);  v += __shfl_xor(v, 4);
      v += __shfl_xor(v, 2);  v += __shfl_xor(v, 1);
      if (t == 0) rtr[0] = 1.f / v;
    }
    __syncthreads();
    const float rT = rtr[0];

    // assemble SN fragments -> SNh/SNl; init P = I fragments -> Ph/Pl
    floatx4 Pf[4];
    #pragma unroll
    for (int nt = 0; nt < 4; ++nt){
      #pragma unroll
      for (int r = 0; r < 4; ++r){
        const int d = w4*16 + q*4 + r;
        const int e = nt*16 + l15;
        float sig = EPSC * (SigmaS[g*4096 + d*64 + e] - 131072.f*cml[d]*cml[e]);
        if (d == e) sig += (1.f/131072.f);
        const float sn = sig * rT;
        const unsigned short hi = f2bf(sn);
        SNh[d*STR + e] = hi;
        SNl[d*STR + e] = f2bf(sn - bf2f(hi));
        const float pv = (d == e) ? 1.f : 0.f;
        Pf[nt][r] = pv;
        Ph[d*STR + e] = f2bf(pv);
        Pl_[d*STR + e] = 0;
      }
    }
    __syncthreads();

    #define MM(AH, AL, BH, BL, OUT)                                            \
    {                                                                          \
      _Pragma("unroll")                                                        \
      for (int nt = 0; nt < 4; ++nt) OUT[nt] = (floatx4){0.f,0.f,0.f,0.f};     \
      _Pragma("unroll")                                                        \
      for (int ks = 0; ks < 2; ++ks){                                          \
        const int ko = ks*32 + q*8;                                            \
        short8 ah = *(const short8*)&AH[(w4*16 + l15)*STR + ko];               \
        short8 al = *(const short8*)&AL[(w4*16 + l15)*STR + ko];               \
        _Pragma("unroll")                                                      \
        for (int nt = 0; nt < 4; ++nt){                                        \
          short8 bh = *(const short8*)&BH[(nt*16 + l15)*STR + ko];             \
          short8 bl = *(const short8*)&BL[(nt*16 + l15)*STR + ko];             \
          OUT[nt] = __builtin_amdgcn_mfma_f32_16x16x32_bf16(ah, bh, OUT[nt], 0,0,0); \
          OUT[nt] = __builtin_amdgcn_mfma_f32_16x16x32_bf16(ah, bl, OUT[nt], 0,0,0); \
          OUT[nt] = __builtin_amdgcn_mfma_f32_16x16x32_bf16(al, bh, OUT[nt], 0,0,0); \
        }                                                                      \
      }                                                                        \
    }

    #define CONV(FR, H, L)                                                     \
    {                                                                          \
      _Pragma("unroll")                                                        \
      for (int nt = 0; nt < 4; ++nt){                                          \
        _Pragma("unroll")                                                      \
        for (int r = 0; r < 4; ++r){                                           \
          const int d = w4*16 + q*4 + r;                                       \
          const int e = nt*16 + l15;                                           \
          const float x = FR[nt][r];                                           \
          const unsigned short hi = f2bf(x);                                   \
          H[d*STR + e] = hi;                                                   \
          L[d*STR + e] = f2bf(x - bf2f(hi));                                   \
        }                                                                      \
      }                                                                        \
    }

    floatx4 Tf[4];
    for (int it = 0; it < 3; ++it){
      MM(Ph, Pl_, Ph, Pl_, Tf);            // T = P*P
      __syncthreads();
      CONV(Tf, Th, Tl);
      __syncthreads();
      MM(Th, Tl, Ph, Pl_, Tf);             // T = P^3
      __syncthreads();
      CONV(Tf, Th, Tl);
      __syncthreads();
      MM(Th, Tl, SNh, SNl, Tf);            // T = P^3 * Sigma_N
      #pragma unroll
      for (int nt = 0; nt < 4; ++nt)
        #pragma unroll
        for (int r = 0; r < 4; ++r)
          Pf[nt][r] = -0.5f*Pf[nt][r] + 1.5f*Tf[nt][r];
      __syncthreads();                      // all done reading Ph/Pl + Th/Tl
      if (it < 2){
        CONV(Pf, Ph, Pl_);
        __syncthreads();
      }
    }

    #pragma unroll
    for (int nt = 0; nt < 4; ++nt)
      #pragma unroll
      for (int r = 0; r < 4; ++r){
        const int d = w4*16 + q*4 + r;
        const int e = nt*16 + l15;
        Pw[g*4096 + d*64 + e] = wsig * Pf[nt][r];
      }
  } else {
    // ---------------- squeeze-excite, one block per n ----------------
    const int n = blockIdx.x - 4;
    const int lane = t & 63, w4 = t >> 6;
    float* xl  = fbuf;         // 256
    float* hb  = fbuf + 256;   // 64
    float* hnb = fbuf + 320;   // 64

    if (t < 64) *(float4*)&xl[t*4] = *(const float4*)&xvar[n*256 + t*4];
    __syncthreads();

    // fc1: h[j] = xl . fc1_w[j][:]   (wave reads one full 1KiB row, coalesced)
    const float4 xv4 = *(const float4*)&xl[lane*4];
    #pragma unroll
    for (int it = 0; it < 16; ++it){
      const int j = w4*16 + it;
      const float4 wv = *(const float4*)&fc1_w[j*256 + lane*4];
      float v = xv4.x*wv.x + xv4.y*wv.y + xv4.z*wv.z + xv4.w*wv.w;
      v += __shfl_down(v, 32); v += __shfl_down(v, 16);
      v += __shfl_down(v, 8);  v += __shfl_down(v, 4);
      v += __shfl_down(v, 2);  v += __shfl_down(v, 1);
      if (lane == 0) hb[j] = v;
    }
    __syncthreads();

    // LayerNorm over 64 (wave 0)
    if (t < 64){
      const float hv = hb[t];
      float s = hv, s2 = hv*hv;
      #pragma unroll
      for (int o = 32; o > 0; o >>= 1){
        s  += __shfl_xor(s,  o);
        s2 += __shfl_xor(s2, o);
      }
      const float mu = s * (1.f/64.f);
      const float var = s2 * (1.f/64.f) - mu*mu;   // biased
      float v = (hv - mu) * rsqrtf(var + LNEPS) * ln_g[t] + ln_b[t];
      hnb[t] = v > 0.f ? v : 0.f;
    }
    __syncthreads();

    // fc2: y[c] = hn . fc2_w[c][:]  (wave covers 4 rows per load, coalesced)
    const float scale = sqrtf(vsum[0] * (1.f/8192.f));
    const float ascl = (1.f - wsig) / scale;
    const int l15 = lane & 15, rgrp = lane >> 4;
    const float4 hn4 = *(const float4*)&hnb[l15*4];
    #pragma unroll
    for (int it = 0; it < 16; ++it){
      const int c = w4*64 + it*4 + rgrp;
      const float4 wv = *(const float4*)&fc2_w[c*64 + l15*4];
      float v = hn4.x*wv.x + hn4.y*wv.y + hn4.z*wv.z + hn4.w*wv.w;
      v += __shfl_down(v, 8); v += __shfl_down(v, 4);
      v += __shfl_down(v, 2); v += __shfl_down(v, 1);
      if (l15 == 0)
        aOut[n*256 + c] = ascl / (1.f + __expf(-v));
    }
  }
}

// ---------------------------------------------------------------------------
// K4: out[n,g*64+d,hw] = sum_e Pw[g][d][e]*X[n,g*64+e,hw] + a[n,c]*X[n,c,hw]
// grid (hwtile=32, g=4, n=32), 256 threads, 128-hw tiles.
// ---------------------------------------------------------------------------
__global__ __launch_bounds__(256) void k_final(
    const float* __restrict__ X, const float* __restrict__ Pw,
    const float* __restrict__ aIn, float* __restrict__ out)
{
  const int bx = blockIdx.x, g = blockIdx.y, n = blockIdx.z;
  const int t = threadIdx.x;
  __shared__ float xt[64*132];
  __shared__ float Pl[4096];
  __shared__ float al[64];

  {
    const int ch = t >> 2, f4 = t & 3;
    const float* rowb = X + (size_t)(n*256 + g*64 + ch)*4096 + bx*128;
    float* ld = xt + ch*132;
    #pragma unroll
    for (int i = 0; i < 8; ++i){
      const int col = (4*i + f4)*4;
      *(float4*)(ld + col) = *(const float4*)(rowb + col);
    }
  }
  #pragma unroll
  for (int i = 0; i < 16; ++i)
    Pl[t + 256*i] = Pw[g*4096 + t + 256*i];
  if (t < 64) al[t] = aIn[n*256 + g*64 + t];
  __syncthreads();

  const int hwq = t & 31, og = t >> 5;
  const float* xcol = xt + hwq*4;
  float4 acc[8];
  #pragma unroll
  for (int dd = 0; dd < 8; ++dd){
    const int d = og*8 + dd;
    float4 xv = *(const float4*)(xcol + d*132);
    const float av = al[d];
    acc[dd].x = av*xv.x; acc[dd].y = av*xv.y; acc[dd].z = av*xv.z; acc[dd].w = av*xv.w;
  }
  for (int e4 = 0; e4 < 16; ++e4){
    float4 x0 = *(const float4*)(xcol + (e4*4 + 0)*132);
    float4 x1 = *(const float4*)(xcol + (e4*4 + 1)*132);
    float4 x2 = *(const float4*)(xcol + (e4*4 + 2)*132);
    float4 x3 = *(const float4*)(xcol + (e4*4 + 3)*132);
    #pragma unroll
    for (int dd = 0; dd < 8; ++dd){
      const int d = og*8 + dd;
      float4 p = *(const float4*)(Pl + d*64 + e4*4);
      acc[dd].x += p.x*x0.x + p.y*x1.x + p.z*x2.x + p.w*x3.x;
      acc[dd].y += p.x*x0.y + p.y*x1.y + p.z*x2.y + p.w*x3.y;
      acc[dd].z += p.x*x0.z + p.y*x1.z + p.z*x2.z + p.w*x3.z;
      acc[dd].w += p.x*x0.w + p.y*x1.w + p.z*x2.w + p.w*x3.w;
    }
  }
  float* ob = out + (size_t)(n*256 + g*64)*4096 + bx*128 + hwq*4;
  #pragma unroll
  for (int dd = 0; dd < 8; ++dd)
    *(float4*)(ob + (size_t)(og*8 + dd)*4096) = acc[dd];
}

// ---------------------------------------------------------------------------
extern "C" void kernel_launch(void* const* d_in, const int* in_sizes, int n_in,
                              void* d_out, int out_size, void* d_ws, size_t ws_size,
                              hipStream_t stream)
{
  const float* X     = (const float*)d_in[0];
  const float* fc1_w = (const float*)d_in[1];
  const float* ln_g  = (const float*)d_in[2];
  const float* ln_b  = (const float*)d_in[3];
  const float* fc2_w = (const float*)d_in[4];
  const float* xw    = (const float*)d_in[5];
  float* out = (float*)d_out;

  char* ws = (char*)d_ws;
  float* gramP  = (float*)ws;                  // 4 MiB
  float* S1p    = (float*)(ws + 4194304);      // 64 KiB
  float* S2p    = (float*)(ws + 4259840);      // 64 KiB
  float* SigmaS = (float*)(ws + 4325376);      // 64 KiB
  float* Pwb    = (float*)(ws + 4390912);      // 64 KiB
  float* aB     = (float*)(ws + 4456448);      // 32 KiB
  float* xvarB  = (float*)(ws + 4489216);      // 32 KiB
  float* cmeanB = (float*)(ws + 4521984);      // 1 KiB
  float* vsumB  = (float*)(ws + 4523008);      // 4 B

  k_stats_gram<<<dim3(2, 4, 32), 256, 0, stream>>>(X, S1p, S2p, gramP);
  k_reduce<<<65, 256, 0, stream>>>(gramP, S1p, S2p, SigmaS, xvarB, cmeanB, vsumB);
  k_mid2<<<36, 256, 0, stream>>>(SigmaS, cmeanB, xvarB, vsumB,
                                 fc1_w, ln_g, ln_b, fc2_w, xw, Pwb, aB);
  k_final<<<dim3(32, 4, 32), 256, 0, stream>>>(X, Pwb, aB, out);
}